// Round 11
// baseline (2900.415 us; speedup 1.0000x reference)
//
#include <hip/hip_runtime.h>

// V=16000 E=512 H=512 L=2 S=128 T=128 B=64; gate dim 4H=2048
// Fused recurrence, per-layer dataflow sync, write-once histories (r9 base):
//  - L0 (WGs 0..31): step t computes [X[t] | h0(t)] @ W0^T -> h0(t+1).
//  - L1 (WGs 32..63): step t computes [y0(t)=h0(t+1) | h1(t)] @ W1^T -> h1(t+1).
// r11 changes vs r9 (layout/scheduling only, same sync protocol):
//  * gate-blocked weight rows rr=(u>>4)*64+g*16+(u&15): MFMA nt-block = gate,
//    activation computed directly from acc registers (pre[] deleted).
//  * both spin waits hoisted to the top of each step; all 32 activation
//    fragments loaded in ONE burst (one L3 latency instead of two).
// Coherence: publishes = sc1 write-through stores + vmcnt(0) + atomic arrive;
// fresh reads = sc1 loads; every exchanged address written once per run.
// WS ~67 MB (<=72 MB proven safe); outWb conversion reuses X after the pipe.

typedef __attribute__((ext_vector_type(8))) short v8s;
typedef __attribute__((ext_vector_type(4))) short v4s;
typedef __attribute__((ext_vector_type(8))) _Float16 v8h;
typedef __attribute__((ext_vector_type(4))) float v4f;
typedef __attribute__((ext_vector_type(4))) unsigned int v4u;

#define AS1 __attribute__((address_space(1)))
#define AS3 __attribute__((address_space(3)))

__device__ __forceinline__ short f2h(float x) {
  _Float16 h = (_Float16)x;
  return __builtin_bit_cast(short, h);
}
__device__ __forceinline__ void gload16(const void* g, void* l) {
  __builtin_amdgcn_global_load_lds((const AS1 void*)g, (AS3 void*)l, 16, 0, 0);
}
__device__ __forceinline__ float sigf(float x) { return 1.f / (1.f + __expf(-x)); }
__device__ __forceinline__ float tanhfast(float x) { return 2.f / (1.f + __expf(-2.f * x)) - 1.f; }

__device__ __forceinline__ void ld16_sc1(v4u& d, const void* p) {
  asm volatile("global_load_dwordx4 %0, %1, off sc1" : "=v"(d) : "v"(p) : "memory");
}
__device__ __forceinline__ void ld16(v4u& d, const void* p) {
  asm volatile("global_load_dwordx4 %0, %1, off" : "=v"(d) : "v"(p));
}
__device__ __forceinline__ void spin_ge(unsigned* p, unsigned tgt) {
  while (__hip_atomic_load(p, __ATOMIC_RELAXED, __HIP_MEMORY_SCOPE_AGENT) < tgt)
    __builtin_amdgcn_s_sleep(1);
}

// ---------- weight convert fp32->fp16 + gate-block reorder:
// input row r = g*512 + u  ->  rr = (u>>4)*64 + g*16 + (u&15)
__global__ void conv_w(const float* __restrict__ in, short* __restrict__ out,
                       int rows, int ldo, int coloff, int reorder) {
  int i = blockIdx.x * 256 + threadIdx.x;       // one float4 per thread
  if (i >= rows * 128) return;                  // K=512 -> 128 quads per row
  int r = i >> 7, k4 = (i & 127) * 4;
  int rr = reorder ? (((r >> 4) & 31) * 64 + (r >> 9) * 16 + (r & 15)) : r;
  float4 v = *(const float4*)(in + (size_t)r * 512 + k4);
  v4s s; s[0] = f2h(v.x); s[1] = f2h(v.y); s[2] = f2h(v.z); s[3] = f2h(v.w);
  *(v4s*)(out + (size_t)rr * ldo + coloff + k4) = s;
}

__global__ void conv_b(const float* __restrict__ a, const float* __restrict__ b,
                       float* __restrict__ o) {
  int r = blockIdx.x * 256 + threadIdx.x;
  if (r < 2048) o[((r >> 4) & 31) * 64 + (r >> 9) * 16 + (r & 15)] = a[r] + b[r];
}

// ---------- embedding gather to fp16
__global__ void embed_k(const int* __restrict__ ids, const float* __restrict__ emb,
                        short* __restrict__ out, int nvalid) {
  int row = blockIdx.x;
  int e = threadIdx.x * 2;
  float2 v = make_float2(0.f, 0.f);
  if (row < nvalid) {
    int id = ids[row];
    v = *(const float2*)(emb + (size_t)id * 512 + e);
  }
  unsigned pack = ((unsigned)(unsigned short)f2h(v.y) << 16) | (unsigned short)f2h(v.x);
  *(unsigned*)(out + (size_t)row * 512 + e) = pack;
}

__global__ void zero_k(short* p, int n) {
  int i = blockIdx.x * 256 + threadIdx.x;
  if (i < n) p[i] = 0;
}

// ---------- GEMM: C[M,N] = A[M,K] * B[N,K]^T (+bias), 128x128 tile, BK=64, fp16
#define GF_BIAS 2
#define GF_GUARDM 4

__global__ __launch_bounds__(256, 2) void gemm_bt(
    const short* __restrict__ Am, const short* __restrict__ Bm,
    const float* __restrict__ bias, float* __restrict__ Cm,
    int M, int N, int K, int ldc, int flags) {
  __shared__ short lA[128 * 64];
  __shared__ short lB[128 * 64];
  const int tid = threadIdx.x, lane = tid & 63, wave = tid >> 6;
  const int wm = wave >> 1, wn = wave & 1;
  const int tm = blockIdx.y, tn = blockIdx.x;
  v4f acc[4][4] = {};
  const short* Abase = Am + (size_t)tm * 128 * K;
  const short* Bbase = Bm + (size_t)tn * 128 * K;

  for (int kt = 0; kt < K; kt += 64) {
    __syncthreads();
#pragma unroll
    for (int i2 = 0; i2 < 4; ++i2) {
      int c = (wave * 4 + i2) * 64 + lane;    // 16B chunk id, 1024 per tile
      int row = c >> 3, ch = c & 7;
      int sch = ch ^ (row & 7);               // inverse swizzle on global source
      gload16(Abase + (size_t)row * K + kt + sch * 8, (char*)lA + (wave * 4 + i2) * 1024);
      gload16(Bbase + (size_t)row * K + kt + sch * 8, (char*)lB + (wave * 4 + i2) * 1024);
    }
    asm volatile("s_waitcnt vmcnt(0)" ::: "memory");
    __syncthreads();
#pragma unroll
    for (int kc = 0; kc < 2; ++kc) {
      v8h af[4], bh[4];
#pragma unroll
      for (int mt = 0; mt < 4; ++mt) {
        int row = wm * 64 + mt * 16 + (lane & 15);
        af[mt] = *(const v8h*)((const char*)lA + row * 128 +
                               ((kc * 64 + (lane >> 4) * 16) ^ ((row & 7) << 4)));
      }
#pragma unroll
      for (int nt = 0; nt < 4; ++nt) {
        int row = wn * 64 + nt * 16 + (lane & 15);
        bh[nt] = *(const v8h*)((const char*)lB + row * 128 +
                               ((kc * 64 + (lane >> 4) * 16) ^ ((row & 7) << 4)));
      }
#pragma unroll
      for (int mt = 0; mt < 4; ++mt)
#pragma unroll
        for (int nt = 0; nt < 4; ++nt)
          acc[mt][nt] = __builtin_amdgcn_mfma_f32_16x16x32_f16(af[mt], bh[nt], acc[mt][nt], 0, 0, 0);
    }
  }

  const int rbase = tm * 128 + wm * 64 + (lane >> 4) * 4;
  const int cbase = tn * 128 + wn * 64 + (lane & 15);
#pragma unroll
  for (int mt = 0; mt < 4; ++mt) {
#pragma unroll
    for (int nt = 0; nt < 4; ++nt) {
      int gc = cbase + nt * 16;
      float bv = (flags & GF_BIAS) ? bias[gc] : 0.f;
#pragma unroll
      for (int rg = 0; rg < 4; ++rg) {
        int gr = rbase + mt * 16 + rg;
        if ((flags & GF_GUARDM) && gr >= M) continue;
        Cm[(size_t)gr * ldc + gc] = acc[mt][nt][rg] + bv;
      }
    }
  }
}

// ---------- fused 2-layer enc+dec LSTM, per-layer dataflow, write-once
struct PipeArgs {
  const short* W0e;  // [2048][1024] fp16 [Wih|Whh], gate-block-reordered rows
  const short* W0d;
  const short* W1e;
  const short* W1d;
  const short* X;    // [255][64][512] fp16 embeddings
  const float* b0e;  // [2048] fp32, gate-block-reordered
  const float* b0d;
  const float* b1e;
  const float* b1d;
  short* h0;         // 256 slots (state s at slot s, write-once)
  short* h1;         // 257 slots
  unsigned* done0;   // [256] counters, stride 32 uints; ==32 <=> state published
  unsigned* done1;
  int Tenc, Ttot;    // 128, 255
};

#define SLOT 32768

__global__ __launch_bounds__(256, 1) void lstm_pipe(PipeArgs A) {
  __shared__ __align__(16) short Wlds[64 * 1024];   // 128 KB
  __shared__ __align__(16) short hsm[64 * 16];      // 2 KB
  const int tid = threadIdx.x, lane = tid & 63, wave = tid >> 6;
  const int w = blockIdx.x, layer = w >> 5, wl = w & 31;

  auto stage = [&](const short* Wsrc) {
    for (int i = tid * 8; i < 64 * 1024; i += 256 * 8) {
      int row = i >> 10, k = i & 1023;
      v8s v = *(const v8s*)(Wsrc + (size_t)row * 1024 + k);
      *(v8s*)((char*)Wlds + row * 2048 + ((k * 2) ^ ((row & 7) << 4))) = v;
    }
  };
  stage((layer ? A.W1e : A.W0e) + (size_t)(wl * 64) * 1024);

  const int uu = lane & 15;
  float beV[4], bdV[4];
#pragma unroll
  for (int g = 0; g < 4; ++g) {
    beV[g] = (layer ? A.b1e : A.b0e)[wl * 64 + g * 16 + uu];
    bdV[g] = (layer ? A.b1d : A.b0d)[wl * 64 + g * 16 + uu];
  }
  float creg[4] = {0.f, 0.f, 0.f, 0.f};
  unsigned* own = layer ? A.done1 : A.done0;

  const int arow = wave * 16 + uu;        // batch row this lane feeds to MFMA A
  const int koff = (lane >> 4) * 8;
  const size_t aoff = (size_t)arow * 512 + koff;
  __syncthreads();

  for (int t = 0; t < A.Ttot; ++t) {
    if (t == A.Tenc) {                    // per-layer decoder weight switch
      stage((layer ? A.W1d : A.W0d) + (size_t)(wl * 64) * 1024);
      __syncthreads();
    }

    // merged waits (same atomic protocol as r9, hoisted to step top)
    if (tid == 0) {
      if (layer) {
        spin_ge(A.done0 + (size_t)(t + 1) * 32, 32u);   // producer y0(t)
        if (t > 0) spin_ge(A.done1 + (size_t)t * 32, 32u);  // own h1(t)
      } else if (t > 0) {
        spin_ge(A.done0 + (size_t)t * 32, 32u);         // own h0(t)
      }
    }
    __syncthreads();

    // single 32-fragment load burst: [input | recurrent]
    const short* p1 = (layer ? (A.h0 + (size_t)(t + 1) * SLOT)
                             : (A.X + (size_t)t * SLOT)) + aoff;
    const short* p2 = ((layer ? A.h1 : A.h0) + (size_t)t * SLOT) + aoff;
    v4u fl[32];
    if (layer) {
#pragma unroll
      for (int kc = 0; kc < 16; ++kc) ld16_sc1(fl[kc], p1 + kc * 32);
    } else {
#pragma unroll
      for (int kc = 0; kc < 16; ++kc) ld16(fl[kc], p1 + kc * 32);
    }
#pragma unroll
    for (int kc = 0; kc < 16; ++kc) ld16_sc1(fl[16 + kc], p2 + kc * 32);
    asm volatile("s_waitcnt vmcnt(0)" ::: "memory");
    __builtin_amdgcn_sched_barrier(0);

    v4f acc[4] = {};
#pragma unroll
    for (int kc = 0; kc < 32; ++kc) {
      v8h af = __builtin_bit_cast(v8h, fl[kc]);
      int kg = kc * 32 + koff;
#pragma unroll
      for (int nt = 0; nt < 4; ++nt) {
        int wrow = nt * 16 + uu;
        v8h bh = *(const v8h*)((const char*)Wlds + wrow * 2048 +
                               ((kg * 2) ^ ((wrow & 7) << 4)));
        acc[nt] = __builtin_amdgcn_mfma_f32_16x16x32_f16(af, bh, acc[nt], 0, 0, 0);
      }
    }

    // activation directly from acc: acc[g][rg] = gate g, batch wave*16+(lane>>4)*4+rg
    {
      const bool enc = t < A.Tenc;
      const float b0v = enc ? beV[0] : bdV[0];
      const float b1v = enc ? beV[1] : bdV[1];
      const float b2v = enc ? beV[2] : bdV[2];
      const float b3v = enc ? beV[3] : bdV[3];
#pragma unroll
      for (int rg = 0; rg < 4; ++rg) {
        float g0 = acc[0][rg] + b0v;
        float g1 = acc[1][rg] + b1v;
        float g2 = acc[2][rg] + b2v;
        float g3 = acc[3][rg] + b3v;
        float c = sigf(g1) * creg[rg] + sigf(g0) * tanhfast(g2);
        creg[rg] = c;
        float h = sigf(g3) * tanhfast(c);
        int bb = wave * 16 + ((lane >> 4) << 2) + rg;
        hsm[bb * 16 + uu] = f2h(h);
      }
    }
    __syncthreads();

    // publish state t+1 (write-once): sc1 stores, drain, sync, atomic arrive
    if (tid < 128) {
      int b = tid >> 1, half = tid & 1;
      v4u d = *(const v4u*)(&hsm[b * 16 + half * 8]);
      short* dst = (layer ? A.h1 : A.h0) + (size_t)(t + 1) * SLOT
                   + b * 512 + wl * 16 + half * 8;
      asm volatile("global_store_dwordx4 %0, %1, off sc1" :: "v"(dst), "v"(d) : "memory");
    }
    asm volatile("s_waitcnt vmcnt(0)" ::: "memory");
    __syncthreads();
    if (tid == 0)
      __hip_atomic_fetch_add(own + (size_t)(t + 1) * 32, 1u,
                             __ATOMIC_RELAXED, __HIP_MEMORY_SCOPE_AGENT);
  }
}

extern "C" void kernel_launch(void* const* d_in, const int* in_sizes, int n_in,
                              void* d_out, int out_size, void* d_ws, size_t ws_size,
                              hipStream_t stream) {
  (void)in_sizes; (void)n_in; (void)out_size; (void)ws_size;
  const int* src = (const int*)d_in[0];
  const int* trg = (const int*)d_in[1];
  const float* enc_emb = (const float*)d_in[3];
  const float* dec_emb = (const float*)d_in[4];
  const float* enc_Wih = (const float*)d_in[5];
  const float* enc_Whh = (const float*)d_in[6];
  const float* enc_bih = (const float*)d_in[7];
  const float* enc_bhh = (const float*)d_in[8];
  const float* dec_Wih = (const float*)d_in[9];
  const float* dec_Whh = (const float*)d_in[10];
  const float* dec_bih = (const float*)d_in[11];
  const float* dec_bhh = (const float*)d_in[12];
  const float* out_W = (const float*)d_in[13];
  const float* out_b = (const float*)d_in[14];

  char* p = (char*)d_ws;
  auto alloc = [&](size_t sz) { char* r = p; p += (sz + 255) & ~(size_t)255; return r; };
  short* H0 = (short*)alloc((size_t)256 * SLOT * 2);       // 16.78 MB, write-once
  short* H1 = (short*)alloc((size_t)257 * SLOT * 2);       // 16.84 MB, write-once
  short* W0e = (short*)alloc((size_t)2048 * 1024 * 2);     // 4 MB each
  short* W0d = (short*)alloc((size_t)2048 * 1024 * 2);
  short* W1e = (short*)alloc((size_t)2048 * 1024 * 2);
  short* W1d = (short*)alloc((size_t)2048 * 1024 * 2);
  short* XO = (short*)alloc((size_t)255 * SLOT * 2);       // 16.71 MB: X, then outWb
  float* bE0 = (float*)alloc(2048 * 4);
  float* bE1 = (float*)alloc(2048 * 4);
  float* bD0 = (float*)alloc(2048 * 4);
  float* bD1 = (float*)alloc(2048 * 4);
  unsigned* done0 = (unsigned*)alloc(256 * 32 * 4);        // 32 KB each
  unsigned* done1 = (unsigned*)alloc(256 * 32 * 4);
  // total ~67 MB (<= 72 MB proven safe)

  // zero: h0 state 0, h1 state 0, h1 pad slot 256, done counters (64 KB)
  zero_k<<<128, 256, 0, stream>>>(H0, 32768);
  zero_k<<<128, 256, 0, stream>>>(H1, 32768);
  zero_k<<<128, 256, 0, stream>>>(H1 + (size_t)256 * SLOT, 32768);
  zero_k<<<128, 256, 0, stream>>>((short*)done0, 32768);

  // weight conversion / reorder: [Wih | Whh] concat, gate-blocked rows
  conv_w<<<1024, 256, 0, stream>>>(enc_Wih, W0e, 2048, 1024, 0, 1);
  conv_w<<<1024, 256, 0, stream>>>(enc_Whh, W0e, 2048, 1024, 512, 1);
  conv_w<<<1024, 256, 0, stream>>>(dec_Wih, W0d, 2048, 1024, 0, 1);
  conv_w<<<1024, 256, 0, stream>>>(dec_Whh, W0d, 2048, 1024, 512, 1);
  conv_w<<<1024, 256, 0, stream>>>(enc_Wih + (size_t)2048 * 512, W1e, 2048, 1024, 0, 1);
  conv_w<<<1024, 256, 0, stream>>>(enc_Whh + (size_t)2048 * 512, W1e, 2048, 1024, 512, 1);
  conv_w<<<1024, 256, 0, stream>>>(dec_Wih + (size_t)2048 * 512, W1d, 2048, 1024, 0, 1);
  conv_w<<<1024, 256, 0, stream>>>(dec_Whh + (size_t)2048 * 512, W1d, 2048, 1024, 512, 1);
  conv_b<<<8, 256, 0, stream>>>(enc_bih, enc_bhh, bE0);
  conv_b<<<8, 256, 0, stream>>>(enc_bih + 2048, enc_bhh + 2048, bE1);
  conv_b<<<8, 256, 0, stream>>>(dec_bih, dec_bhh, bD0);
  conv_b<<<8, 256, 0, stream>>>(dec_bih + 2048, dec_bhh + 2048, bD1);

  // embeddings: enc -> X slots 0..127, dec -> slots 128..254
  embed_k<<<8192, 256, 0, stream>>>(src, enc_emb, XO, 8192);
  embed_k<<<8128, 256, 0, stream>>>(trg, dec_emb, XO + (size_t)8192 * 512, 8128);

  // fused encoder+decoder recurrence (per-layer dataflow, write-once)
  PipeArgs pa = {W0e, W0d, W1e, W1d, XO, bE0, bD0, bE1, bD1,
                 H0, H1, done0, done1, 128, 255};
  lstm_pipe<<<64, 256, 0, stream>>>(pa);

  // outWb conversion reuses X's region (X dead after the pipe; stream-ordered)
  short* outWb = XO;
  conv_w<<<8000, 256, 0, stream>>>(out_W, outWb, 16000, 512, 0, 0);

  // logits = H1 slots 129..255 (+pad) @ out_W^T + out_b -> fp32 d_out
  gemm_bt<<<dim3(125, 64), 256, 0, stream>>>(H1 + (size_t)129 * SLOT, outWb, out_b,
                                             (float*)d_out, 8128, 16000, 512, 16000,
                                             GF_BIAS | GF_GUARDM);
}

// Round 12
// 2343.678 us; speedup vs baseline: 1.2375x; 1.2375x over previous
//
#include <hip/hip_runtime.h>

// V=16000 E=512 H=512 L=2 S=128 T=128 B=64; gate dim 4H=2048
// Fused recurrence, per-layer dataflow, write-once histories (r9 structure):
//  - L0 (WGs 0..31): step t: [X[t] | h0(t)] @ W0^T -> h0(t+1) at H0[t+1].
//  - L1 (WGs 32..63): step t: [y0(t)=h0(t+1) | h1(t)] @ W1^T -> h1(t+1).
// r12 vs r9:
//  * gate-blocked weight rows rr=(u>>4)*64+g*16+(u&15) (r11-proven): MFMA
//    nt-block = gate -> activation directly from acc regs (no pre[] LDS).
//  * arrival = per-WG flag word (64B stride), single plain sc1 dword store
//    (== clang's agent-relaxed atomic-store lowering); NO serialized RMW.
//  * detection = wave-0 lane-parallel poll: 32 lanes load 32 flags in one
//    instruction (independent lines, one L3 latency) + __all.
//  * phase order preserved from r9 (waits interleaved with compute --
//    r11 proved hoisting them regresses).
// Coherence: publishes = sc1 write-through stores, per-wave vmcnt(0) drain,
// syncthreads, then flag store; fresh reads = sc1 loads; every exchanged
// data address written once per run (no stale-clean-line hazard).
// WS ~67 MB (<=72 MB proven safe; >=140 MB failed = overflow).

typedef __attribute__((ext_vector_type(8))) short v8s;
typedef __attribute__((ext_vector_type(4))) short v4s;
typedef __attribute__((ext_vector_type(8))) _Float16 v8h;
typedef __attribute__((ext_vector_type(4))) float v4f;
typedef __attribute__((ext_vector_type(4))) unsigned int v4u;

#define AS1 __attribute__((address_space(1)))
#define AS3 __attribute__((address_space(3)))

__device__ __forceinline__ short f2h(float x) {
  _Float16 h = (_Float16)x;
  return __builtin_bit_cast(short, h);
}
__device__ __forceinline__ void gload16(const void* g, void* l) {
  __builtin_amdgcn_global_load_lds((const AS1 void*)g, (AS3 void*)l, 16, 0, 0);
}
__device__ __forceinline__ float sigf(float x) { return 1.f / (1.f + __expf(-x)); }
__device__ __forceinline__ float tanhfast(float x) { return 2.f / (1.f + __expf(-2.f * x)) - 1.f; }

__device__ __forceinline__ void ld16_sc1(v4u& d, const void* p) {
  asm volatile("global_load_dwordx4 %0, %1, off sc1" : "=v"(d) : "v"(p) : "memory");
}
__device__ __forceinline__ void ld16(v4u& d, const void* p) {
  asm volatile("global_load_dwordx4 %0, %1, off" : "=v"(d) : "v"(p));
}

// wave-0 lane-parallel flag poll: lanes 0..31 check flags[(base+lane)*16] >= tgt
__device__ __forceinline__ void poll32(const unsigned* flags, int base, unsigned tgt) {
  int lane = threadIdx.x & 63;
  const unsigned* fp = flags + (size_t)(base + (lane & 31)) * 16;
  while (true) {
    unsigned v;
    asm volatile("global_load_dword %0, %1, off sc1\n\ts_waitcnt vmcnt(0)"
                 : "=v"(v) : "v"(fp) : "memory");
    if (__all((int)((lane >= 32) || (v >= tgt)))) break;
    __builtin_amdgcn_s_sleep(1);
  }
}

// ---------- weight convert fp32->fp16 + gate-block reorder:
// input row r = g*512 + u  ->  rr = (u>>4)*64 + g*16 + (u&15)
__global__ void conv_w(const float* __restrict__ in, short* __restrict__ out,
                       int rows, int ldo, int coloff, int reorder) {
  int i = blockIdx.x * 256 + threadIdx.x;       // one float4 per thread
  if (i >= rows * 128) return;                  // K=512 -> 128 quads per row
  int r = i >> 7, k4 = (i & 127) * 4;
  int rr = reorder ? (((r >> 4) & 31) * 64 + (r >> 9) * 16 + (r & 15)) : r;
  float4 v = *(const float4*)(in + (size_t)r * 512 + k4);
  v4s s; s[0] = f2h(v.x); s[1] = f2h(v.y); s[2] = f2h(v.z); s[3] = f2h(v.w);
  *(v4s*)(out + (size_t)rr * ldo + coloff + k4) = s;
}

__global__ void conv_b(const float* __restrict__ a, const float* __restrict__ b,
                       float* __restrict__ o) {
  int r = blockIdx.x * 256 + threadIdx.x;
  if (r < 2048) o[((r >> 4) & 31) * 64 + (r >> 9) * 16 + (r & 15)] = a[r] + b[r];
}

// ---------- embedding gather to fp16
__global__ void embed_k(const int* __restrict__ ids, const float* __restrict__ emb,
                        short* __restrict__ out, int nvalid) {
  int row = blockIdx.x;
  int e = threadIdx.x * 2;
  float2 v = make_float2(0.f, 0.f);
  if (row < nvalid) {
    int id = ids[row];
    v = *(const float2*)(emb + (size_t)id * 512 + e);
  }
  unsigned pack = ((unsigned)(unsigned short)f2h(v.y) << 16) | (unsigned short)f2h(v.x);
  *(unsigned*)(out + (size_t)row * 512 + e) = pack;
}

__global__ void zero_k(short* p, int n) {
  int i = blockIdx.x * 256 + threadIdx.x;
  if (i < n) p[i] = 0;
}

// ---------- GEMM: C[M,N] = A[M,K] * B[N,K]^T (+bias), 128x128 tile, BK=64, fp16
#define GF_BIAS 2
#define GF_GUARDM 4

__global__ __launch_bounds__(256, 2) void gemm_bt(
    const short* __restrict__ Am, const short* __restrict__ Bm,
    const float* __restrict__ bias, float* __restrict__ Cm,
    int M, int N, int K, int ldc, int flags) {
  __shared__ short lA[128 * 64];
  __shared__ short lB[128 * 64];
  const int tid = threadIdx.x, lane = tid & 63, wave = tid >> 6;
  const int wm = wave >> 1, wn = wave & 1;
  const int tm = blockIdx.y, tn = blockIdx.x;
  v4f acc[4][4] = {};
  const short* Abase = Am + (size_t)tm * 128 * K;
  const short* Bbase = Bm + (size_t)tn * 128 * K;

  for (int kt = 0; kt < K; kt += 64) {
    __syncthreads();
#pragma unroll
    for (int i2 = 0; i2 < 4; ++i2) {
      int c = (wave * 4 + i2) * 64 + lane;    // 16B chunk id, 1024 per tile
      int row = c >> 3, ch = c & 7;
      int sch = ch ^ (row & 7);               // inverse swizzle on global source
      gload16(Abase + (size_t)row * K + kt + sch * 8, (char*)lA + (wave * 4 + i2) * 1024);
      gload16(Bbase + (size_t)row * K + kt + sch * 8, (char*)lB + (wave * 4 + i2) * 1024);
    }
    asm volatile("s_waitcnt vmcnt(0)" ::: "memory");
    __syncthreads();
#pragma unroll
    for (int kc = 0; kc < 2; ++kc) {
      v8h af[4], bh[4];
#pragma unroll
      for (int mt = 0; mt < 4; ++mt) {
        int row = wm * 64 + mt * 16 + (lane & 15);
        af[mt] = *(const v8h*)((const char*)lA + row * 128 +
                               ((kc * 64 + (lane >> 4) * 16) ^ ((row & 7) << 4)));
      }
#pragma unroll
      for (int nt = 0; nt < 4; ++nt) {
        int row = wn * 64 + nt * 16 + (lane & 15);
        bh[nt] = *(const v8h*)((const char*)lB + row * 128 +
                               ((kc * 64 + (lane >> 4) * 16) ^ ((row & 7) << 4)));
      }
#pragma unroll
      for (int mt = 0; mt < 4; ++mt)
#pragma unroll
        for (int nt = 0; nt < 4; ++nt)
          acc[mt][nt] = __builtin_amdgcn_mfma_f32_16x16x32_f16(af[mt], bh[nt], acc[mt][nt], 0, 0, 0);
    }
  }

  const int rbase = tm * 128 + wm * 64 + (lane >> 4) * 4;
  const int cbase = tn * 128 + wn * 64 + (lane & 15);
#pragma unroll
  for (int mt = 0; mt < 4; ++mt) {
#pragma unroll
    for (int nt = 0; nt < 4; ++nt) {
      int gc = cbase + nt * 16;
      float bv = (flags & GF_BIAS) ? bias[gc] : 0.f;
#pragma unroll
      for (int rg = 0; rg < 4; ++rg) {
        int gr = rbase + mt * 16 + rg;
        if ((flags & GF_GUARDM) && gr >= M) continue;
        Cm[(size_t)gr * ldc + gc] = acc[mt][nt][rg] + bv;
      }
    }
  }
}

// ---------- fused 2-layer enc+dec LSTM, per-layer dataflow, write-once
struct PipeArgs {
  const short* W0e;  // [2048][1024] fp16 [Wih|Whh], gate-block-reordered rows
  const short* W0d;
  const short* W1e;
  const short* W1d;
  const short* X;    // [255][64][512] fp16 embeddings
  const float* b0e;  // [2048] fp32, gate-block-reordered
  const float* b0d;
  const float* b1e;
  const float* b1d;
  short* h0;         // 256 slots (state s at slot s, write-once)
  short* h1;         // 257 slots
  unsigned* flags;   // [64] per-WG step flags, stride 16 dwords (64B)
  int Tenc, Ttot;    // 128, 255
};

#define SLOT 32768

__global__ __launch_bounds__(256, 1) void lstm_pipe(PipeArgs A) {
  __shared__ __align__(16) short Wlds[64 * 1024];   // 128 KB
  __shared__ __align__(16) short hsm[64 * 16];      // 2 KB
  const int tid = threadIdx.x, lane = tid & 63, wave = tid >> 6;
  const int w = blockIdx.x, layer = w >> 5, wl = w & 31;

  auto stage = [&](const short* Wsrc) {
    for (int i = tid * 8; i < 64 * 1024; i += 256 * 8) {
      int row = i >> 10, k = i & 1023;
      v8s v = *(const v8s*)(Wsrc + (size_t)row * 1024 + k);
      *(v8s*)((char*)Wlds + row * 2048 + ((k * 2) ^ ((row & 7) << 4))) = v;
    }
  };
  stage((layer ? A.W1e : A.W0e) + (size_t)(wl * 64) * 1024);

  const int uu = lane & 15;
  float beV[4], bdV[4];
#pragma unroll
  for (int g = 0; g < 4; ++g) {
    beV[g] = (layer ? A.b1e : A.b0e)[wl * 64 + g * 16 + uu];
    bdV[g] = (layer ? A.b1d : A.b0d)[wl * 64 + g * 16 + uu];
  }
  float creg[4] = {0.f, 0.f, 0.f, 0.f};

  const int arow = wave * 16 + uu;        // batch row this lane feeds to MFMA A
  const int koff = (lane >> 4) * 8;
  const size_t aoff = (size_t)arow * 512 + koff;
  __syncthreads();

  for (int t = 0; t < A.Ttot; ++t) {
    if (t == A.Tenc) {                    // per-layer decoder weight switch
      stage((layer ? A.W1d : A.W0d) + (size_t)(wl * 64) * 1024);
      __syncthreads();
    }

    v4f acc[4] = {};

    // ---- phase 1: input half. L0: X[t] (static, no wait). L1: y0(t), gated.
    if (layer) {
      if (wave == 0) poll32(A.flags, 0, (unsigned)(t + 1));   // producer L0
      __syncthreads();
    }
    {
      const short* p1 = (layer ? (A.h0 + (size_t)(t + 1) * SLOT)
                               : (A.X + (size_t)t * SLOT)) + aoff;
      v4u fa[16];
      if (layer) {
#pragma unroll
        for (int kc = 0; kc < 16; ++kc) ld16_sc1(fa[kc], p1 + kc * 32);
      } else {
#pragma unroll
        for (int kc = 0; kc < 16; ++kc) ld16(fa[kc], p1 + kc * 32);
      }
      asm volatile("s_waitcnt vmcnt(0)" ::: "memory");
      __builtin_amdgcn_sched_barrier(0);
#pragma unroll
      for (int kc = 0; kc < 16; ++kc) {
        v8h af = __builtin_bit_cast(v8h, fa[kc]);
        int kg = kc * 32 + koff;
#pragma unroll
        for (int nt = 0; nt < 4; ++nt) {
          int wrow = nt * 16 + uu;
          v8h bh = *(const v8h*)((const char*)Wlds + wrow * 2048 +
                                 ((kg * 2) ^ ((wrow & 7) << 4)));
          acc[nt] = __builtin_amdgcn_mfma_f32_16x16x32_f16(af, bh, acc[nt], 0, 0, 0);
        }
      }
    }

    // ---- phase 2: recurrent half (own-layer h state t)
    if (t > 0) {
      if (wave == 0) poll32(A.flags, layer ? 32 : 0, (unsigned)t);
      __syncthreads();
    }
    {
      const short* p2 = ((layer ? A.h1 : A.h0) + (size_t)t * SLOT) + aoff;
      v4u fb[16];
#pragma unroll
      for (int kc = 0; kc < 16; ++kc) ld16_sc1(fb[kc], p2 + kc * 32);
      asm volatile("s_waitcnt vmcnt(0)" ::: "memory");
      __builtin_amdgcn_sched_barrier(0);
#pragma unroll
      for (int kc = 0; kc < 16; ++kc) {
        v8h af = __builtin_bit_cast(v8h, fb[kc]);
        int kg = (kc + 16) * 32 + koff;
#pragma unroll
        for (int nt = 0; nt < 4; ++nt) {
          int wrow = nt * 16 + uu;
          v8h bh = *(const v8h*)((const char*)Wlds + wrow * 2048 +
                                 ((kg * 2) ^ ((wrow & 7) << 4)));
          acc[nt] = __builtin_amdgcn_mfma_f32_16x16x32_f16(af, bh, acc[nt], 0, 0, 0);
        }
      }
    }

    // activation directly from acc: acc[g][rg] = gate g, batch wave*16+(lane>>4)*4+rg
    {
      const bool enc = t < A.Tenc;
      const float b0v = enc ? beV[0] : bdV[0];
      const float b1v = enc ? beV[1] : bdV[1];
      const float b2v = enc ? beV[2] : bdV[2];
      const float b3v = enc ? beV[3] : bdV[3];
#pragma unroll
      for (int rg = 0; rg < 4; ++rg) {
        float g0 = acc[0][rg] + b0v;
        float g1 = acc[1][rg] + b1v;
        float g2 = acc[2][rg] + b2v;
        float g3 = acc[3][rg] + b3v;
        float c = sigf(g1) * creg[rg] + sigf(g0) * tanhfast(g2);
        creg[rg] = c;
        float h = sigf(g3) * tanhfast(c);
        int bb = wave * 16 + ((lane >> 4) << 2) + rg;
        hsm[bb * 16 + uu] = f2h(h);
      }
    }
    __syncthreads();

    // publish state t+1 (write-once): sc1 stores, per-wave drain, sync, flag
    if (tid < 128) {
      int b = tid >> 1, half = tid & 1;
      v4u d = *(const v4u*)(&hsm[b * 16 + half * 8]);
      short* dst = (layer ? A.h1 : A.h0) + (size_t)(t + 1) * SLOT
                   + b * 512 + wl * 16 + half * 8;
      asm volatile("global_store_dwordx4 %0, %1, off sc1" :: "v"(dst), "v"(d) : "memory");
    }
    asm volatile("s_waitcnt vmcnt(0)" ::: "memory");
    __syncthreads();                       // all waves' data stores drained
    if (tid == 0) {
      unsigned val = (unsigned)(t + 1);
      const unsigned* fp = A.flags + (size_t)w * 16;
      asm volatile("global_store_dword %0, %1, off sc1" :: "v"(fp), "v"(val) : "memory");
    }
  }
}

extern "C" void kernel_launch(void* const* d_in, const int* in_sizes, int n_in,
                              void* d_out, int out_size, void* d_ws, size_t ws_size,
                              hipStream_t stream) {
  (void)in_sizes; (void)n_in; (void)out_size; (void)ws_size;
  const int* src = (const int*)d_in[0];
  const int* trg = (const int*)d_in[1];
  const float* enc_emb = (const float*)d_in[3];
  const float* dec_emb = (const float*)d_in[4];
  const float* enc_Wih = (const float*)d_in[5];
  const float* enc_Whh = (const float*)d_in[6];
  const float* enc_bih = (const float*)d_in[7];
  const float* enc_bhh = (const float*)d_in[8];
  const float* dec_Wih = (const float*)d_in[9];
  const float* dec_Whh = (const float*)d_in[10];
  const float* dec_bih = (const float*)d_in[11];
  const float* dec_bhh = (const float*)d_in[12];
  const float* out_W = (const float*)d_in[13];
  const float* out_b = (const float*)d_in[14];

  char* p = (char*)d_ws;
  auto alloc = [&](size_t sz) { char* r = p; p += (sz + 255) & ~(size_t)255; return r; };
  short* H0 = (short*)alloc((size_t)256 * SLOT * 2);       // 16.78 MB, write-once
  short* H1 = (short*)alloc((size_t)257 * SLOT * 2);       // 16.84 MB, write-once
  short* W0e = (short*)alloc((size_t)2048 * 1024 * 2);     // 4 MB each
  short* W0d = (short*)alloc((size_t)2048 * 1024 * 2);
  short* W1e = (short*)alloc((size_t)2048 * 1024 * 2);
  short* W1d = (short*)alloc((size_t)2048 * 1024 * 2);
  short* XO = (short*)alloc((size_t)255 * SLOT * 2);       // 16.71 MB: X, then outWb
  float* bE0 = (float*)alloc(2048 * 4);
  float* bE1 = (float*)alloc(2048 * 4);
  float* bD0 = (float*)alloc(2048 * 4);
  float* bD1 = (float*)alloc(2048 * 4);
  unsigned* flags = (unsigned*)alloc(64 * 16 * 4);         // 4 KB
  // total ~67 MB (<= 72 MB proven safe)

  // zero: h0 state 0, h1 state 0, h1 pad slot 256, flags
  zero_k<<<128, 256, 0, stream>>>(H0, 32768);
  zero_k<<<128, 256, 0, stream>>>(H1, 32768);
  zero_k<<<128, 256, 0, stream>>>(H1 + (size_t)256 * SLOT, 32768);
  zero_k<<<8, 256, 0, stream>>>((short*)flags, 2048);

  // weight conversion / reorder: [Wih | Whh] concat, gate-blocked rows
  conv_w<<<1024, 256, 0, stream>>>(enc_Wih, W0e, 2048, 1024, 0, 1);
  conv_w<<<1024, 256, 0, stream>>>(enc_Whh, W0e, 2048, 1024, 512, 1);
  conv_w<<<1024, 256, 0, stream>>>(dec_Wih, W0d, 2048, 1024, 0, 1);
  conv_w<<<1024, 256, 0, stream>>>(dec_Whh, W0d, 2048, 1024, 512, 1);
  conv_w<<<1024, 256, 0, stream>>>(enc_Wih + (size_t)2048 * 512, W1e, 2048, 1024, 0, 1);
  conv_w<<<1024, 256, 0, stream>>>(enc_Whh + (size_t)2048 * 512, W1e, 2048, 1024, 512, 1);
  conv_w<<<1024, 256, 0, stream>>>(dec_Wih + (size_t)2048 * 512, W1d, 2048, 1024, 0, 1);
  conv_w<<<1024, 256, 0, stream>>>(dec_Whh + (size_t)2048 * 512, W1d, 2048, 1024, 512, 1);
  conv_b<<<8, 256, 0, stream>>>(enc_bih, enc_bhh, bE0);
  conv_b<<<8, 256, 0, stream>>>(enc_bih + 2048, enc_bhh + 2048, bE1);
  conv_b<<<8, 256, 0, stream>>>(dec_bih, dec_bhh, bD0);
  conv_b<<<8, 256, 0, stream>>>(dec_bih + 2048, dec_bhh + 2048, bD1);

  // embeddings: enc -> X slots 0..127, dec -> slots 128..254
  embed_k<<<8192, 256, 0, stream>>>(src, enc_emb, XO, 8192);
  embed_k<<<8128, 256, 0, stream>>>(trg, dec_emb, XO + (size_t)8192 * 512, 8128);

  // fused encoder+decoder recurrence (per-layer dataflow, write-once, flags)
  PipeArgs pa = {W0e, W0d, W1e, W1d, XO, bE0, bD0, bE1, bD1,
                 H0, H1, flags, 128, 255};
  lstm_pipe<<<64, 256, 0, stream>>>(pa);

  // outWb conversion reuses X's region (X dead after the pipe; stream-ordered)
  short* outWb = XO;
  conv_w<<<8000, 256, 0, stream>>>(out_W, outWb, 16000, 512, 0, 0);

  // logits = H1 slots 129..255 (+pad) @ out_W^T + out_b -> fp32 d_out
  gemm_bt<<<dim3(125, 64), 256, 0, stream>>>(H1 + (size_t)129 * SLOT, outWb, out_b,
                                             (float*)d_out, 8128, 16000, 512, 16000,
                                             GF_BIAS | GF_GUARDM);
}